// Round 5
// baseline (281.624 us; speedup 1.0000x reference)
//
#include <hip/hip_runtime.h>
#include <hip/hip_bf16.h>

#define B_ 64
#define N_ 4096
#define F_ 512
#define D_ 256
#define BM 32
#define APAD 520                 // halves per LDS row (1040 B)
#define NCHUNK (N_ / BM)         // 128 chunks per batch
#define NBLK (B_ * NCHUNK)       // 8192 blocks

typedef __attribute__((ext_vector_type(8))) short short8;
typedef __attribute__((ext_vector_type(4))) float f32x4;

__device__ __forceinline__ unsigned short f2bf(float f) {
  unsigned int u = __float_as_uint(f);
  u += 0x7FFFu + ((u >> 16) & 1u);   // RNE round to bf16
  return (unsigned short)(u >> 16);
}

__device__ __forceinline__ unsigned int pk2bf(float x, float y) {
  float2 f; f.x = x; f.y = y;
  __hip_bfloat162 h = __float22bfloat162_rn(f);   // v_cvt_pk_bf16_f32
  union { __hip_bfloat162 h2; unsigned int u; } cv; cv.h2 = h;
  return cv.u;                                    // x in low 16 bits
}

__device__ __forceinline__ float fast_tanh(float x) {
  float e = __expf(-2.0f * fabsf(x));
  float t = (1.0f - e) / (1.0f + e);
  return copysignf(t, x);
}

// raw barrier: no vmcnt drain (keeps producer loads in flight)
#define SBAR                                                                   \
  do {                                                                         \
    __builtin_amdgcn_sched_barrier(0);                                         \
    __builtin_amdgcn_s_barrier();                                              \
    __builtin_amdgcn_sched_barrier(0);                                         \
  } while (0)

// producer: drain LDS writes before barrier (rule #18: sched fence after)
#define LGKM0                                                                  \
  do {                                                                         \
    asm volatile("s_waitcnt lgkmcnt(0)" ::: "memory");                         \
    __builtin_amdgcn_sched_barrier(0);                                         \
  } while (0)

// ---- prep: W_img f32 [256][512] -> bf16 in exact MFMA B-fragment order.
// q = K-step-32 index (0..15). idx = ((q*16 + d16)*64 + lane)*8 + e
__global__ void prep_w_kernel(const float* __restrict__ Wimg,
                              unsigned short* __restrict__ wfrag) {
  int d = blockIdx.x;        // 0..255
  int f = threadIdx.x;       // 0..511
  int q = f >> 5, lg = (f >> 3) & 3, e = f & 7;
  int lr = d & 15, d16 = d >> 4;
  int lane = lg * 16 + lr;
  int idx = ((q * 16 + d16) * 64 + lane) * 8 + e;
  wfrag[idx] = f2bf(Wimg[d * F_ + f]);
}

// ---- prep: proj_hidden[b][d]
__global__ void prep_ph_kernel(const float* __restrict__ hid,
                               const float* __restrict__ Whid,
                               float* __restrict__ ph) {
  int b = blockIdx.x, d = threadIdx.x;  // 64 x 256
  const float4* hv = (const float4*)(hid + b * F_);
  const float4* wv = (const float4*)(Whid + d * F_);
  float acc = 0.f;
#pragma unroll 4
  for (int i = 0; i < 128; i++) {
    float4 h = hv[i], w = wv[i];
    acc += h.x * w.x + h.y * w.y + h.z * w.z + h.w * w.w;
  }
  ph[b * D_ + d] = acc;
}

// ---- fused: producer/consumer GEMM + tanh + score + softmax partial + ctx partial
__global__ __launch_bounds__(512, 2) void fused_kernel(
    const float* __restrict__ feat, const unsigned short* __restrict__ wfrag,
    const float* __restrict__ ph, const float* __restrict__ wscore,
    float* __restrict__ expw, float2* __restrict__ meta,
    float* __restrict__ part) {
  __shared__ unsigned short Afull[BM * APAD];  // 33.3 KiB bf16 feat tile
  __shared__ float red[BM][4];
  __shared__ float sbuf[BM];
  __shared__ float ewf[BM];

  int tid = threadIdx.x;
  int lane = tid & 63, wid = tid >> 6;
  int lr = lane & 15, lg = lane >> 4;
  bool prod = (wid < 4);
  int cw = prod ? 0 : (wid - 4);           // consumer d-group 0..3

  int blk = blockIdx.x;                    // 8192
  int b = blk >> 7, chunk = blk & 127;
  int n0 = chunk * BM;

  const float* arow = feat + (size_t)(b * N_ + n0) * F_;

  // consumer accumulators (live across whole K-loop)
  f32x4 acc0[4], acc1[4];
#pragma unroll
  for (int n = 0; n < 4; n++) { acc0[n] = (f32x4)0.f; acc1[n] = (f32x4)0.f; }

  // producer addressing: 256 producer threads, 4 float4 each per 128-col phase
  int ptid = tid & 255;
  int r2_[4], c4_[4];
#pragma unroll
  for (int i = 0; i < 4; i++) {
    int idx4 = ptid + i * 256;
    r2_[i] = idx4 >> 5;          // row 0..31
    c4_[i] = idx4 & 31;          // float4 col 0..31 within phase
  }
  float4 ra0[4], ra1[4];         // 2-deep producer pipeline

#define LOADA(buf, p_)                                                         \
  _Pragma("unroll") for (int i = 0; i < 4; i++)                                \
      buf[i] = *(const float4*)(arow + (size_t)r2_[i] * F_ + (p_)*128 + c4_[i] * 4);

#define CVT(buf, p_)                                                           \
  _Pragma("unroll") for (int i = 0; i < 4; i++) {                              \
    unsigned int p0 = pk2bf(buf[i].x, buf[i].y);                               \
    unsigned int p1 = pk2bf(buf[i].z, buf[i].w);                               \
    *(uint2*)(Afull + r2_[i] * APAD + (p_)*128 + c4_[i] * 4) = make_uint2(p0, p1); \
  }

  const unsigned short* bbase = wfrag + (size_t)((cw * 4) * 64 + lane) * 8;

// consumer: one K-step-32 q — B frags from L2, A frags from LDS, 8 MFMAs
#define QSTEP(q_)                                                              \
  {                                                                            \
    short8 bf[4];                                                              \
    _Pragma("unroll") for (int n = 0; n < 4; n++)                              \
        bf[n] = *(const short8*)(bbase + (size_t)(((q_)*16 + n) * 64) * 8);    \
    short8 a0 = *(const short8*)(Afull + lr * APAD + (q_)*32 + lg * 8);        \
    short8 a1 = *(const short8*)(Afull + (16 + lr) * APAD + (q_)*32 + lg * 8); \
    _Pragma("unroll") for (int n = 0; n < 4; n++) {                            \
      acc0[n] = __builtin_amdgcn_mfma_f32_16x16x32_bf16(a0, bf[n], acc0[n], 0, 0, 0); \
      acc1[n] = __builtin_amdgcn_mfma_f32_16x16x32_bf16(a1, bf[n], acc1[n], 0, 0, 0); \
    }                                                                          \
  }

#define PHASE(p_) { QSTEP((p_)*4+0); QSTEP((p_)*4+1); QSTEP((p_)*4+2); QSTEP((p_)*4+3); }

  // prologue: stage phase 0; keep phase-1 loads in flight across the barrier
  if (prod) { LOADA(ra0, 0); LOADA(ra1, 1); CVT(ra0, 0); LGKM0; }
  SBAR;
  // phase 0: consumers chew p0; producers issue p2, write p1
  if (prod) { LOADA(ra0, 2); CVT(ra1, 1); LGKM0; } else { PHASE(0); }
  SBAR;
  // phase 1
  if (prod) { LOADA(ra1, 3); CVT(ra0, 2); LGKM0; } else { PHASE(1); }
  SBAR;
  // phase 2
  if (prod) { CVT(ra1, 3); LGKM0; } else { PHASE(2); }
  SBAR;
  // phase 3 + score reduction (consumers only)
  if (!prod) {
    PHASE(3);
    float ph4[4], wv4[4];
#pragma unroll
    for (int n = 0; n < 4; n++) {
      int d = cw * 64 + n * 16 + lr;
      ph4[n] = ph[b * D_ + d];
      wv4[n] = wscore[d];
    }
#pragma unroll
    for (int m = 0; m < 2; m++) {
#pragma unroll
      for (int j = 0; j < 4; j++) {
        float p = 0.f;
#pragma unroll
        for (int n = 0; n < 4; n++) {
          float v = (m == 0) ? acc0[n][j] : acc1[n][j];
          p += fast_tanh(v + ph4[n]) * wv4[n];
        }
        p += __shfl_xor(p, 1);
        p += __shfl_xor(p, 2);
        p += __shfl_xor(p, 4);
        p += __shfl_xor(p, 8);
        if (lr == 0) red[m * 16 + lg * 4 + j][cw] = p;
      }
    }
  }
  __syncthreads();
  if (tid < BM) sbuf[tid] = red[tid][0] + red[tid][1] + red[tid][2] + red[tid][3];
  __syncthreads();

  // block-local softmax partials
  float mb = -1e30f;
#pragma unroll
  for (int r = 0; r < BM; r++) mb = fmaxf(mb, sbuf[r]);
  if (tid < BM) {
    float e = __expf(sbuf[tid] - mb);
    ewf[tid] = e;
    expw[b * N_ + n0 + tid] = e;
    float l = e;
#pragma unroll
    for (int o = 1; o < 32; o <<= 1) l += __shfl_xor(l, o);
    if (tid == 0) meta[blk] = make_float2(mb, l);
  }
  __syncthreads();

  // ---- context partial from LDS bf16 tile (256 threads, 2 cols each)
  if (tid < 256) {
    int f0 = tid * 2;
    float a0 = 0.f, a1 = 0.f;
#pragma unroll 8
    for (int r = 0; r < BM; r++) {
      float w = ewf[r];
      unsigned int v = *(const unsigned int*)(Afull + r * APAD + f0);
      a0 += w * __uint_as_float(v << 16);
      a1 += w * __uint_as_float(v & 0xffff0000u);
    }
    float2 o; o.x = a0; o.y = a1;
    *(float2*)(part + (size_t)blk * F_ + f0) = o;
  }
}

// ---- finalize per batch: global softmax merge + context combine + weights
__global__ void finalize_kernel(const float* __restrict__ part,
                                const float2* __restrict__ meta,
                                const float* __restrict__ expw,
                                float* __restrict__ ctx,
                                float* __restrict__ wout) {
  __shared__ float sm[NCHUNK], sl[NCHUNK], se[NCHUNK];
  int b = blockIdx.x, t = threadIdx.x;   // 512 threads
  if (t < NCHUNK) {
    float2 ml = meta[b * NCHUNK + t];
    sm[t] = ml.x;
    sl[t] = ml.y;
  }
  __syncthreads();
  float M = -1e30f;
#pragma unroll 8
  for (int i = 0; i < NCHUNK; i++) M = fmaxf(M, sm[i]);
  float Z = 0.f;
#pragma unroll 8
  for (int i = 0; i < NCHUNK; i++) Z += sl[i] * __expf(sm[i] - M);
  if (t < NCHUNK) se[t] = __expf(sm[t] - M);
  __syncthreads();
  float invZ = 1.0f / Z;
  float acc = 0.f;
#pragma unroll 8
  for (int i = 0; i < NCHUNK; i++) acc += part[(size_t)(b * NCHUNK + i) * F_ + t] * se[i];
  ctx[b * F_ + t] = acc * invZ;
#pragma unroll
  for (int k = 0; k < 8; k++) {
    int n = k * 512 + t;
    wout[b * N_ + n] = expw[b * N_ + n] * se[n >> 5] * invZ;
  }
}

extern "C" void kernel_launch(void* const* d_in, const int* in_sizes, int n_in,
                              void* d_out, int out_size, void* d_ws, size_t ws_size,
                              hipStream_t stream) {
  const float* feat   = (const float*)d_in[0];   // [64,4096,512]
  const float* hid    = (const float*)d_in[1];   // [64,512]
  const float* Wimg   = (const float*)d_in[2];   // [256,512]
  const float* Whid   = (const float*)d_in[3];   // [256,512]
  const float* Wscore = (const float*)d_in[4];   // [1,256]

  float* ctx  = (float*)d_out;            // [64,512]
  float* wout = (float*)d_out + B_ * F_;  // [64,4096]

  // workspace layout
  unsigned short* wfrag = (unsigned short*)d_ws;                 // 256 KiB
  float*  ph    = (float*)((char*)d_ws + 262144);                // 64 KiB
  float*  expw  = (float*)((char*)d_ws + 327680);                // 1 MiB
  float2* meta  = (float2*)((char*)d_ws + 1376256);              // 64 KiB
  float*  part  = (float*)((char*)d_ws + 1441792);               // 16 MiB

  prep_w_kernel<<<D_, F_, 0, stream>>>(Wimg, wfrag);
  prep_ph_kernel<<<B_, D_, 0, stream>>>(hid, Whid, ph);
  fused_kernel<<<NBLK, 512, 0, stream>>>(feat, wfrag, ph, Wscore, expw, meta, part);
  finalize_kernel<<<B_, 512, 0, stream>>>(part, meta, expw, ctx, wout);
}

// Round 6
// 214.213 us; speedup vs baseline: 1.3147x; 1.3147x over previous
//
#include <hip/hip_runtime.h>
#include <hip/hip_bf16.h>

#define B_ 64
#define N_ 4096
#define F_ 512
#define D_ 256
#define BM 32
#define APAD 520                 // halves per LDS row (1040 B)
#define NCHUNK (N_ / BM)         // 128 chunks per batch
#define NBLK (B_ * NCHUNK)       // 8192 blocks

typedef __attribute__((ext_vector_type(8))) short short8;
typedef __attribute__((ext_vector_type(4))) float f32x4;

__device__ __forceinline__ unsigned short f2bf(float f) {
  unsigned int u = __float_as_uint(f);
  u += 0x7FFFu + ((u >> 16) & 1u);   // RNE round to bf16
  return (unsigned short)(u >> 16);
}

__device__ __forceinline__ unsigned int pk2bf(float x, float y) {
  float2 f; f.x = x; f.y = y;
  __hip_bfloat162 h = __float22bfloat162_rn(f);   // v_cvt_pk_bf16_f32
  union { __hip_bfloat162 h2; unsigned int u; } cv; cv.h2 = h;
  return cv.u;                                    // x in low 16 bits
}

__device__ __forceinline__ float fast_tanh(float x) {
  float e = __expf(-2.0f * fabsf(x));
  float t = (1.0f - e) / (1.0f + e);
  return copysignf(t, x);
}

// raw barrier: no vmcnt drain (global prefetch loads stay in flight)
#define SBAR                                                                   \
  do {                                                                         \
    __builtin_amdgcn_sched_barrier(0);                                         \
    __builtin_amdgcn_s_barrier();                                              \
    __builtin_amdgcn_sched_barrier(0);                                         \
  } while (0)

// drain LDS writes before barrier (rule #18: sched fence after)
#define LGKM0                                                                  \
  do {                                                                         \
    asm volatile("s_waitcnt lgkmcnt(0)" ::: "memory");                         \
    __builtin_amdgcn_sched_barrier(0);                                         \
  } while (0)

// ---- prep: W_img f32 [256][512] -> bf16 in exact MFMA B-fragment order.
// q = K-step-32 index (0..15). idx = ((q*16 + d16)*64 + lane)*8 + e
__global__ void prep_w_kernel(const float* __restrict__ Wimg,
                              unsigned short* __restrict__ wfrag) {
  int d = blockIdx.x;        // 0..255
  int f = threadIdx.x;       // 0..511
  int q = f >> 5, lg = (f >> 3) & 3, e = f & 7;
  int lr = d & 15, d16 = d >> 4;
  int lane = lg * 16 + lr;
  int idx = ((q * 16 + d16) * 64 + lane) * 8 + e;
  wfrag[idx] = f2bf(Wimg[d * F_ + f]);
}

// ---- prep: proj_hidden[b][d]
__global__ void prep_ph_kernel(const float* __restrict__ hid,
                               const float* __restrict__ Whid,
                               float* __restrict__ ph) {
  int b = blockIdx.x, d = threadIdx.x;  // 64 x 256
  const float4* hv = (const float4*)(hid + b * F_);
  const float4* wv = (const float4*)(Whid + d * F_);
  float acc = 0.f;
#pragma unroll 4
  for (int i = 0; i < 128; i++) {
    float4 h = hv[i], w = wv[i];
    acc += h.x * w.x + h.y * w.y + h.z * w.z + h.w * w.w;
  }
  ph[b * D_ + d] = acc;
}

// ---- fused: GEMM + tanh + score + block softmax partial + ctx partial
__global__ __launch_bounds__(256, 4) void fused_kernel(
    const float* __restrict__ feat, const unsigned short* __restrict__ wfrag,
    const float* __restrict__ ph, const float* __restrict__ wscore,
    float* __restrict__ expw, float2* __restrict__ meta,
    float* __restrict__ part) {
  __shared__ unsigned short Afull[BM * APAD];  // 33.3 KiB bf16 feat tile
  __shared__ float red[BM][4];
  __shared__ float sbuf[BM];
  __shared__ float ewf[BM];

  int tid = threadIdx.x;
  int lane = tid & 63, wn = tid >> 6;
  int lr = lane & 15, lg = lane >> 4;

  int blk = blockIdx.x;                    // 8192
  int b = blk >> 7, chunk = blk & 127;
  int n0 = chunk * BM;

  const float* arow = feat + (size_t)(b * N_ + n0) * F_;

  f32x4 acc[2][4];
#pragma unroll
  for (int m = 0; m < 2; m++)
#pragma unroll
    for (int n = 0; n < 4; n++) acc[m][n] = (f32x4)0.f;

  int r2_[4], c4_[4];
#pragma unroll
  for (int i = 0; i < 4; i++) {
    int idx4 = tid + i * 256;   // float4 index within 32x128 phase slice
    r2_[i] = idx4 >> 5;         // row 0..31
    c4_[i] = idx4 & 31;         // float4 col 0..31 within phase
  }

  float4 ra0[4], ra1[4];        // 2-deep A pipeline (static names, rule #20)

#define LOADA(buf, p_)                                                         \
  _Pragma("unroll") for (int i = 0; i < 4; i++)                                \
      buf[i] = *(const float4*)(arow + (size_t)r2_[i] * F_ + (p_)*128 + c4_[i] * 4);

#define CVT(buf, p_)                                                           \
  _Pragma("unroll") for (int i = 0; i < 4; i++) {                              \
    unsigned int p0 = pk2bf(buf[i].x, buf[i].y);                               \
    unsigned int p1 = pk2bf(buf[i].z, buf[i].w);                               \
    *(uint2*)(Afull + r2_[i] * APAD + (p_)*128 + c4_[i] * 4) = make_uint2(p0, p1); \
  }

  const unsigned short* bbase = wfrag + (size_t)((wn * 4) * 64 + lane) * 8;

// one K-step-32 q: 4 B frags (L2), 2 A frags (LDS), 8 MFMAs
#define QSTEP(q_)                                                              \
  {                                                                            \
    short8 bf[4];                                                              \
    _Pragma("unroll") for (int n = 0; n < 4; n++)                              \
        bf[n] = *(const short8*)(bbase + (size_t)(((q_)*16 + n) * 64) * 8);    \
    short8 a0 = *(const short8*)(Afull + lr * APAD + (q_)*32 + lg * 8);        \
    short8 a1 = *(const short8*)(Afull + (16 + lr) * APAD + (q_)*32 + lg * 8); \
    _Pragma("unroll") for (int n = 0; n < 4; n++) {                            \
      acc[0][n] = __builtin_amdgcn_mfma_f32_16x16x32_bf16(a0, bf[n], acc[0][n], 0, 0, 0); \
      acc[1][n] = __builtin_amdgcn_mfma_f32_16x16x32_bf16(a1, bf[n], acc[1][n], 0, 0, 0); \
    }                                                                          \
  }

#define PHASE(p_) { QSTEP((p_)*4+0); QSTEP((p_)*4+1); QSTEP((p_)*4+2); QSTEP((p_)*4+3); }

  // prologue: issue p0+p1 loads, write p0, barrier (p1 loads stay in flight)
  LOADA(ra0, 0);
  LOADA(ra1, 1);
  CVT(ra0, 0);                 // counted vmcnt: waits only ra0's 4 loads
  LGKM0;
  SBAR;
  // phase 0: issue p2, compute p0, write p1 (write-late, T14)
  LOADA(ra0, 2);
  PHASE(0);
  CVT(ra1, 1);
  LGKM0;
  SBAR;
  // phase 1: issue p3, compute p1, write p2
  LOADA(ra1, 3);
  PHASE(1);
  CVT(ra0, 2);
  LGKM0;
  SBAR;
  // phase 2: compute p2, write p3
  PHASE(2);
  CVT(ra1, 3);
  LGKM0;
  SBAR;
  // phase 3: compute p3
  PHASE(3);

  // ---- scores: s[row] = sum_d tanh(proj + ph) * wscore
  float ph4[4], wv4[4];
#pragma unroll
  for (int n = 0; n < 4; n++) {
    int d = wn * 64 + n * 16 + lr;
    ph4[n] = ph[b * D_ + d];
    wv4[n] = wscore[d];
  }
#pragma unroll
  for (int m = 0; m < 2; m++) {
#pragma unroll
    for (int j = 0; j < 4; j++) {
      float p = 0.f;
#pragma unroll
      for (int n = 0; n < 4; n++)
        p += fast_tanh(acc[m][n][j] + ph4[n]) * wv4[n];
      p += __shfl_xor(p, 1);
      p += __shfl_xor(p, 2);
      p += __shfl_xor(p, 4);
      p += __shfl_xor(p, 8);
      if (lr == 0) red[m * 16 + lg * 4 + j][wn] = p;
    }
  }
  __syncthreads();
  if (tid < BM) sbuf[tid] = red[tid][0] + red[tid][1] + red[tid][2] + red[tid][3];
  __syncthreads();

  // block-local softmax partials
  float mb = -1e30f;
#pragma unroll
  for (int r = 0; r < BM; r++) mb = fmaxf(mb, sbuf[r]);
  if (tid < BM) {
    float e = __expf(sbuf[tid] - mb);
    ewf[tid] = e;
    expw[b * N_ + n0 + tid] = e;
    float l = e;
#pragma unroll
    for (int o = 1; o < 32; o <<= 1) l += __shfl_xor(l, o);
    if (tid == 0) meta[blk] = make_float2(mb, l);
  }
  __syncthreads();

  // ---- context partial from LDS bf16 tile
  int f0 = tid * 2;
  float a0 = 0.f, a1 = 0.f;
#pragma unroll 8
  for (int r = 0; r < BM; r++) {
    float w = ewf[r];
    unsigned int v = *(const unsigned int*)(Afull + r * APAD + f0);
    a0 += w * __uint_as_float(v << 16);
    a1 += w * __uint_as_float(v & 0xffff0000u);
  }
  float2 o; o.x = a0; o.y = a1;
  *(float2*)(part + (size_t)blk * F_ + f0) = o;
}

// ---- finalize per batch: global softmax merge + context combine + weights
__global__ void finalize_kernel(const float* __restrict__ part,
                                const float2* __restrict__ meta,
                                const float* __restrict__ expw,
                                float* __restrict__ ctx,
                                float* __restrict__ wout) {
  __shared__ float sm[NCHUNK], sl[NCHUNK], se[NCHUNK];
  int b = blockIdx.x, t = threadIdx.x;   // 512 threads
  if (t < NCHUNK) {
    float2 ml = meta[b * NCHUNK + t];
    sm[t] = ml.x;
    sl[t] = ml.y;
  }
  __syncthreads();
  float M = -1e30f;
#pragma unroll 8
  for (int i = 0; i < NCHUNK; i++) M = fmaxf(M, sm[i]);
  float Z = 0.f;
#pragma unroll 8
  for (int i = 0; i < NCHUNK; i++) Z += sl[i] * __expf(sm[i] - M);
  if (t < NCHUNK) se[t] = __expf(sm[t] - M);
  __syncthreads();
  float invZ = 1.0f / Z;
  float acc = 0.f;
#pragma unroll 8
  for (int i = 0; i < NCHUNK; i++) acc += part[(size_t)(b * NCHUNK + i) * F_ + t] * se[i];
  ctx[b * F_ + t] = acc * invZ;
#pragma unroll
  for (int k = 0; k < 8; k++) {
    int n = k * 512 + t;
    wout[b * N_ + n] = expw[b * N_ + n] * se[n >> 5] * invZ;
  }
}

extern "C" void kernel_launch(void* const* d_in, const int* in_sizes, int n_in,
                              void* d_out, int out_size, void* d_ws, size_t ws_size,
                              hipStream_t stream) {
  const float* feat   = (const float*)d_in[0];   // [64,4096,512]
  const float* hid    = (const float*)d_in[1];   // [64,512]
  const float* Wimg   = (const float*)d_in[2];   // [256,512]
  const float* Whid   = (const float*)d_in[3];   // [256,512]
  const float* Wscore = (const float*)d_in[4];   // [1,256]

  float* ctx  = (float*)d_out;            // [64,512]
  float* wout = (float*)d_out + B_ * F_;  // [64,4096]

  // workspace layout
  unsigned short* wfrag = (unsigned short*)d_ws;                 // 256 KiB
  float*  ph    = (float*)((char*)d_ws + 262144);                // 64 KiB
  float*  expw  = (float*)((char*)d_ws + 327680);                // 1 MiB
  float2* meta  = (float2*)((char*)d_ws + 1376256);              // 64 KiB
  float*  part  = (float*)((char*)d_ws + 1441792);               // 16 MiB

  prep_w_kernel<<<D_, F_, 0, stream>>>(Wimg, wfrag);
  prep_ph_kernel<<<B_, D_, 0, stream>>>(hid, Whid, ph);
  fused_kernel<<<NBLK, 256, 0, stream>>>(feat, wfrag, ph, Wscore, expw, meta, part);
  finalize_kernel<<<B_, 512, 0, stream>>>(part, meta, expw, ctx, wout);
}